// Round 1
// baseline (61.755 us; speedup 1.0000x reference)
//
#include <hip/hip_runtime.h>
#include <math.h>

#define TPB 256

constexpr int Bn    = 131072;
constexpr int Nn    = 8;
constexpr int F_INn = 30;
constexpr int Hn    = 3;
constexpr float ALPHAc = 0.2f;
constexpr float NEGc   = -9.0e15f;

__global__ __launch_bounds__(TPB)
void gat_ppo_kernel(const float* __restrict__ xg,
                    const float* __restrict__ adjg,
                    const float* __restrict__ Wg,
                    const float* __restrict__ ahg,
                    const float* __restrict__ wog,
                    const float* __restrict__ aog,
                    const float* __restrict__ muWg,
                    const float* __restrict__ mubg,
                    const float* __restrict__ sgWg,
                    const float* __restrict__ sgbg,
                    const float* __restrict__ vWg,
                    const float* __restrict__ vbg,
                    float* __restrict__ outg)
{
    __shared__ float xs[TPB * F_INn];  // 7680 floats = 30 KB

    const int lb = threadIdx.x;
    const int t  = blockIdx.x * TPB + lb;   // global row index = b*8 + n
    const int n  = lb & 7;                  // node id

    // ---- stage x tile (32 batches * 8 nodes * 30 feats) coalesced ----
    {
        const float2* src = (const float2*)(xg) + (size_t)blockIdx.x * (TPB * F_INn / 2);
        float2* dst = (float2*)xs;
        #pragma unroll
        for (int k = 0; k < 15; ++k)
            dst[lb + k * TPB] = src[lb + k * TPB];
    }

    // ---- adj row: 8 consecutive floats per thread, coalesced ----
    float adjr[8];
    {
        const float4* a4 = (const float4*)(adjg) + (size_t)t * 2;
        float4 a0 = a4[0], a1 = a4[1];
        adjr[0] = a0.x; adjr[1] = a0.y; adjr[2] = a0.z; adjr[3] = a0.w;
        adjr[4] = a1.x; adjr[5] = a1.y; adjr[6] = a1.z; adjr[7] = a1.w;
    }

    __syncthreads();

    // ---- x row into registers ----
    float x[F_INn];
    {
        const float2* xr = (const float2*)(xs) + lb * (F_INn / 2);
        #pragma unroll
        for (int k = 0; k < 15; ++k) {
            float2 v = xr[k];
            x[2 * k] = v.x; x[2 * k + 1] = v.y;
        }
    }

    // ---- Wh[h][o] = sum_f x[f] * W[h][f][o];  f1/f2 per head ----
    float wh[Hn][8];
    float f1v[Hn], f2v[Hn];
    #pragma unroll
    for (int h = 0; h < Hn; ++h) {
        #pragma unroll
        for (int o = 0; o < 8; ++o) wh[h][o] = 0.0f;
        #pragma unroll
        for (int f = 0; f < F_INn; ++f) {
            #pragma unroll
            for (int o = 0; o < 8; ++o)
                wh[h][o] = fmaf(x[f], Wg[h * 240 + f * 8 + o], wh[h][o]);
        }
        float s1 = 0.0f, s2 = 0.0f;
        #pragma unroll
        for (int o = 0; o < 8; ++o) {
            s1 = fmaf(wh[h][o], ahg[h * 16 + o],     s1);
            s2 = fmaf(wh[h][o], ahg[h * 16 + 8 + o], s2);
        }
        f1v[h] = s1; f2v[h] = s2;
    }

    // ---- per-head masked softmax attention + aggregation + elu + W_out fold ----
    float wh2 = 0.0f;
    #pragma unroll
    for (int h = 0; h < Hn; ++h) {
        float p[8];
        float mx = NEGc;
        #pragma unroll
        for (int m = 0; m < 8; ++m) {
            float f2m = __shfl(f2v[h], m, 8);
            float ev = f1v[h] + f2m;
            ev = (ev > 0.0f) ? ev : ALPHAc * ev;          // leaky_relu
            ev = (adjr[m] > 0.0f) ? ev : NEGc;            // mask
            p[m] = ev;
            mx = fmaxf(mx, ev);
        }
        float s = 0.0f;
        #pragma unroll
        for (int m = 0; m < 8; ++m) {
            float pe = (adjr[m] > 0.0f) ? __expf(p[m] - mx) : 0.0f;
            p[m] = pe; s += pe;
        }
        float rs = 1.0f / s;

        float hacc[8];
        #pragma unroll
        for (int o = 0; o < 8; ++o) hacc[o] = 0.0f;
        #pragma unroll
        for (int m = 0; m < 8; ++m) {
            float attm = p[m] * rs;
            #pragma unroll
            for (int o = 0; o < 8; ++o) {
                float whm = __shfl(wh[h][o], m, 8);
                hacc[o] = fmaf(attm, whm, hacc[o]);
            }
        }
        #pragma unroll
        for (int o = 0; o < 8; ++o) {
            float hv = hacc[o];
            hv = (hv > 0.0f) ? hv : (__expf(hv) - 1.0f);  // elu
            wh2 = fmaf(hv, wog[h * 8 + o], wh2);          // h @ W_out
        }
    }

    // ---- second GAT layer on Wh2 (scalar per node) ----
    const float a0c = aog[0], a1c = aog[1];
    float wh2a[8];
    #pragma unroll
    for (int m = 0; m < 8; ++m) wh2a[m] = __shfl(wh2, m, 8);

    float g1 = a0c * wh2;
    float p2[8]; float mx2 = NEGc;
    #pragma unroll
    for (int m = 0; m < 8; ++m) {
        float ev = fmaf(a1c, wh2a[m], g1);
        ev = (ev > 0.0f) ? ev : ALPHAc * ev;
        ev = (adjr[m] > 0.0f) ? ev : NEGc;
        p2[m] = ev; mx2 = fmaxf(mx2, ev);
    }
    float s2 = 0.0f;
    #pragma unroll
    for (int m = 0; m < 8; ++m) {
        float pe = (adjr[m] > 0.0f) ? __expf(p2[m] - mx2) : 0.0f;
        p2[m] = pe; s2 += pe;
    }
    float rs2 = 1.0f / s2;
    float og = 0.0f;
    #pragma unroll
    for (int m = 0; m < 8; ++m) og = fmaf(p2[m] * rs2, wh2a[m], og);
    float g = (og > 0.0f) ? og : (__expf(og) - 1.0f);     // elu -> g[b][n]

    // ---- MLP heads: mu, sigma (per node j=n), value (per batch) ----
    float gall[8];
    #pragma unroll
    for (int m = 0; m < 8; ++m) gall[m] = __shfl(g, m, 8);

    float mu = mubg[n];
    float sg = sgbg[n];
    float vv = vbg[0];
    #pragma unroll
    for (int k = 0; k < 8; ++k) {
        mu = fmaf(gall[k], muWg[n * 8 + k], mu);
        sg = fmaf(gall[k], sgWg[n * 8 + k], sg);
        vv = fmaf(gall[k], vWg[k],          vv);
    }
    mu = 1.0f / (1.0f + __expf(-mu));                               // sigmoid
    sg = fmaxf(sg, 0.0f) + log1pf(__expf(-fabsf(sg))) + 0.001f;     // softplus + 1e-3

    outg[t]          = mu;
    outg[Bn * 8 + t] = sg;
    if (n == 0) outg[Bn * 16 + (t >> 3)] = vv;
}

extern "C" void kernel_launch(void* const* d_in, const int* in_sizes, int n_in,
                              void* d_out, int out_size, void* d_ws, size_t ws_size,
                              hipStream_t stream) {
    const float* xg   = (const float*)d_in[0];
    const float* adjg = (const float*)d_in[1];
    const float* Wg   = (const float*)d_in[2];
    const float* ahg  = (const float*)d_in[3];
    const float* wog  = (const float*)d_in[4];
    const float* aog  = (const float*)d_in[5];
    const float* muW  = (const float*)d_in[6];
    const float* mub  = (const float*)d_in[7];
    const float* sgW  = (const float*)d_in[8];
    const float* sgb  = (const float*)d_in[9];
    const float* vW   = (const float*)d_in[10];
    const float* vb   = (const float*)d_in[11];
    float* outg = (float*)d_out;

    dim3 grid(Bn * Nn / TPB);  // 4096 blocks of 256 threads; 8 lanes per batch
    gat_ppo_kernel<<<grid, TPB, 0, stream>>>(xg, adjg, Wg, ahg, wog, aog,
                                             muW, mub, sgW, sgb, vW, vb, outg);
}